// Round 9
// baseline (290.793 us; speedup 1.0000x reference)
//
#include <hip/hip_runtime.h>

#define HW_   (512 * 512)   // pixels per image
#define NIMG  8
#define NC    19            // classes
#define NSP   2048          // superpixels per image
#define TC    20            // target row stride (C+1, last col sliced off)
#define NROWS (NIMG * NSP)  // 16384 target rows
#define TILE  4096          // pixels per block (16 per thread)
#define NBLK  512           // blocks (2 per CU); 512*4096 = all 2Mpx, one shot
#define NGRP  16            // completion-ticket groups (32 blocks each)

typedef float vf4 __attribute__((ext_vector_type(4)));
typedef int   vi4 __attribute__((ext_vector_type(4)));

// d_ws layout:
//   [0]    flag (uint)       spmask width: 1 -> 4-byte, 0 -> 1-byte
//   [4]    st   (uint)       super ticket
//   [64]   gt[NGRP] uints, stride 16 (64 B apart -> no same-line RMWs)
//   [1088] pl[NBLK] float    per-block loss partials (contention-free)
//   [3136] pc[NBLK] uint     per-block count partials
//   [5184] bmt[NROWS] uint   per-(image,superpixel) multi-hot bitmask

// ---------------------------------------------------------------------------
// Kernel 1: zero tickets, detect spmask width, build target bitmasks.
// (logic unchanged since round 5; see comments there)
// ---------------------------------------------------------------------------
__global__ __launch_bounds__(256) void prep(
    const float* __restrict__ tgt,
    const unsigned int* __restrict__ spm,
    unsigned int* __restrict__ flag, unsigned int* __restrict__ st,
    unsigned int* __restrict__ gt, unsigned int* __restrict__ bm) {

    int gid = blockIdx.x * 256 + threadIdx.x;
    if (gid == 0) *st = 0u;
    if (gid < NGRP) gt[gid * 16] = 0u;

    if (blockIdx.x == 1 && threadIdx.x < 64) {
        unsigned int nonlow = 0, upper = 0;
        for (int i = threadIdx.x; i < 1024; i += 64) {
            unsigned int v = spm[i];
            nonlow |= (v & 0xFEFEFEFEu);
            upper  |= (v & 0xFFFFFF00u);
        }
        unsigned long long b1 = __ballot(nonlow != 0);
        unsigned long long b2 = __ballot(upper != 0);
        if (threadIdx.x == 0)
            *flag = ((b1 == 0ull) && (b2 != 0ull)) ? 0u : 1u;
    }

    const float* row = tgt + (size_t)gid * TC;
    unsigned int m = 0;
#pragma unroll
    for (int c = 0; c < NC; ++c)
        m |= (row[c] != 0.0f ? 1u : 0u) << c;
    bm[gid] = m;
}

// ---------------------------------------------------------------------------
// Kernel 2: contiguous-run, rolling-vmcnt pipelined exp-sum + NLL.
// THEORY: rounds 1-8 switched memory stream on EVERY vmem instruction
// (19 class rows 1 MB apart) -> fixed ~275-500 cyc/instr chip-wide
// (DRAM-row / translation thrash). Fills & m13 copy (contiguous per wave)
// hit 6.3-6.8 TB/s. This kernel makes each wave's runs 4 KB contiguous
// (4 consecutive dwordx4 per class) and never drains the pipe:
// 5-set register window, each step issues class c+4 then waits vmcnt(16)
// (4 classes always in flight), consumes class c. "+v" pass-through pins
// consumption after the wait; "memory" clobbers keep compiler vmem out of
// the chain (its waits would corrupt the vmcnt bookkeeping).
// ---------------------------------------------------------------------------

// Issue 4 contiguous dwordx4 for the next class into set Q, advance vo 1 MB,
// wait until only 16 loads (4 classes) remain, pinning consumable set P.
#define STEPS(Q0,Q1,Q2,Q3,P0,P1,P2,P3)                                     \
    asm volatile(                                                          \
        "global_load_dwordx4 %[q0], %[vo], %[xb]\n\t"                      \
        "global_load_dwordx4 %[q1], %[vo], %[xb] offset:1024\n\t"          \
        "global_load_dwordx4 %[q2], %[vo], %[xb] offset:2048\n\t"          \
        "global_load_dwordx4 %[q3], %[vo], %[xb] offset:3072\n\t"          \
        "v_add_u32 %[vo], 0x100000, %[vo]\n\t"                             \
        "s_waitcnt vmcnt(16)"                                              \
        : [q0]"=v"(Q0), [q1]"=v"(Q1), [q2]"=v"(Q2), [q3]"=v"(Q3),          \
          [p0]"+v"(P0), [p1]"+v"(P1), [p2]"+v"(P2), [p3]"+v"(P3),          \
          [vo]"+v"(vo)                                                     \
        : [xb]"s"(xb) : "memory")

#define WAITP(P0,P1,P2,P3,W)                                               \
    asm volatile("s_waitcnt vmcnt(" #W ")"                                 \
        : [p0]"+v"(P0), [p1]"+v"(P1), [p2]"+v"(P2), [p3]"+v"(P3)           \
        :: "memory")

#define ACC(Q,i,c) {                                                       \
    float e0 = __expf((Q).x), e1 = __expf((Q).y);                          \
    float e2 = __expf((Q).z), e3 = __expf((Q).w);                          \
    se[i][0] += e0; se[i][1] += e1; se[i][2] += e2; se[i][3] += e3;        \
    ts[i][0] += ((bmv[i][0] >> (c)) & 1) ? e0 : 0.0f;                      \
    ts[i][1] += ((bmv[i][1] >> (c)) & 1) ? e1 : 0.0f;                      \
    ts[i][2] += ((bmv[i][2] >> (c)) & 1) ? e2 : 0.0f;                      \
    ts[i][3] += ((bmv[i][3] >> (c)) & 1) ? e3 : 0.0f; }

#define CONSUME(S0,S1,S2,S3,c) ACC(S0,0,c) ACC(S1,1,c) ACC(S2,2,c) ACC(S3,3,c)

__global__ __launch_bounds__(256, 2) void mcce_main(
    const float* __restrict__ x,      // (N, C, H*W)
    const int*   __restrict__ sp,     // (N, H*W)
    const void*  __restrict__ spm,    // (N, H*W) mask, 1B or 4B elements
    const unsigned int* __restrict__ bmt,   // (N*NSP) bitmasks
    const unsigned int* __restrict__ flag,
    float* __restrict__ pl, unsigned int* __restrict__ pc,
    unsigned int* __restrict__ st, unsigned int* __restrict__ gt,
    float* __restrict__ out) {

    __shared__ float sL[4];
    __shared__ unsigned int sC[4];

    int b = blockIdx.x, t = threadIdx.x;
    int wave = t >> 6, lane = t & 63;
    int n   = b >> 6;                  // 64 blocks per image
    int pib = (b & 63) * TILE;         // pixel base within image
    int wp  = wave * 1024 + lane * 4;  // wave+lane pixel offset in tile

    const float* xb  = x  + (size_t)n * NC * HW_ + pib;
    const int*   spb = sp + (size_t)n * HW_ + pib;
    unsigned int flagv = *flag;

    // ---- per-pixel metadata, fully consumed BEFORE the streaming chain ----
    vi4 sq[4];
#pragma unroll
    for (int i = 0; i < 4; ++i)
        sq[i] = *(const vi4*)(spb + wp + i * 256);

    int mk[4][4];
    if (flagv) {                       // wave-uniform width branch
#pragma unroll
        for (int i = 0; i < 4; ++i) {
            vi4 m = *(const vi4*)((const int*)spm + (size_t)n * HW_ + pib + wp + i * 256);
            mk[i][0] = m.x; mk[i][1] = m.y; mk[i][2] = m.z; mk[i][3] = m.w;
        }
    } else {
#pragma unroll
        for (int i = 0; i < 4; ++i) {
            unsigned int mw = *(const unsigned int*)
                ((const unsigned char*)spm + (size_t)n * HW_ + pib + wp + i * 256);
            mk[i][0] = mw & 0xFF; mk[i][1] = (mw >> 8) & 0xFF;
            mk[i][2] = (mw >> 16) & 0xFF; mk[i][3] = (mw >> 24) & 0xFF;
        }
    }

    const unsigned int* bt = bmt + n * NSP;
    unsigned int bmv[4][4];            // bitmask, pre-ANDed with spmask
    bmv[0][0] = mk[0][0] ? bt[sq[0].x] : 0u;
    bmv[0][1] = mk[0][1] ? bt[sq[0].y] : 0u;
    bmv[0][2] = mk[0][2] ? bt[sq[0].z] : 0u;
    bmv[0][3] = mk[0][3] ? bt[sq[0].w] : 0u;
    bmv[1][0] = mk[1][0] ? bt[sq[1].x] : 0u;
    bmv[1][1] = mk[1][1] ? bt[sq[1].y] : 0u;
    bmv[1][2] = mk[1][2] ? bt[sq[1].z] : 0u;
    bmv[1][3] = mk[1][3] ? bt[sq[1].w] : 0u;
    bmv[2][0] = mk[2][0] ? bt[sq[2].x] : 0u;
    bmv[2][1] = mk[2][1] ? bt[sq[2].y] : 0u;
    bmv[2][2] = mk[2][2] ? bt[sq[2].z] : 0u;
    bmv[2][3] = mk[2][3] ? bt[sq[2].w] : 0u;
    bmv[3][0] = mk[3][0] ? bt[sq[3].x] : 0u;
    bmv[3][1] = mk[3][1] ? bt[sq[3].y] : 0u;
    bmv[3][2] = mk[3][2] ? bt[sq[3].z] : 0u;
    bmv[3][3] = mk[3][3] ? bt[sq[3].w] : 0u;

    // ---- rolling-window streaming chain ----
    float se[4][4] = {{0,0,0,0},{0,0,0,0},{0,0,0,0},{0,0,0,0}};
    float ts[4][4] = {{0,0,0,0},{0,0,0,0},{0,0,0,0},{0,0,0,0}};
    unsigned int vo = (unsigned int)(wave * 4096 + lane * 16);

    vf4 A0,A1,A2,A3, B0,B1,B2,B3, C0,C1,C2,C3, D0,D1,D2,D3, E0,E1,E2,E3;

    // Prologue: issue classes 0..3 into A,B,C,D (16 loads, no wait).
    asm volatile(
        "global_load_dwordx4 %[a0], %[vo], %[xb]\n\t"
        "global_load_dwordx4 %[a1], %[vo], %[xb] offset:1024\n\t"
        "global_load_dwordx4 %[a2], %[vo], %[xb] offset:2048\n\t"
        "global_load_dwordx4 %[a3], %[vo], %[xb] offset:3072\n\t"
        "v_add_u32 %[vo], 0x100000, %[vo]\n\t"
        "global_load_dwordx4 %[b0], %[vo], %[xb]\n\t"
        "global_load_dwordx4 %[b1], %[vo], %[xb] offset:1024\n\t"
        "global_load_dwordx4 %[b2], %[vo], %[xb] offset:2048\n\t"
        "global_load_dwordx4 %[b3], %[vo], %[xb] offset:3072\n\t"
        "v_add_u32 %[vo], 0x100000, %[vo]\n\t"
        "global_load_dwordx4 %[c0], %[vo], %[xb]\n\t"
        "global_load_dwordx4 %[c1], %[vo], %[xb] offset:1024\n\t"
        "global_load_dwordx4 %[c2], %[vo], %[xb] offset:2048\n\t"
        "global_load_dwordx4 %[c3], %[vo], %[xb] offset:3072\n\t"
        "v_add_u32 %[vo], 0x100000, %[vo]\n\t"
        "global_load_dwordx4 %[d0], %[vo], %[xb]\n\t"
        "global_load_dwordx4 %[d1], %[vo], %[xb] offset:1024\n\t"
        "global_load_dwordx4 %[d2], %[vo], %[xb] offset:2048\n\t"
        "global_load_dwordx4 %[d3], %[vo], %[xb] offset:3072\n\t"
        "v_add_u32 %[vo], 0x100000, %[vo]"
        : [a0]"=v"(A0),[a1]"=v"(A1),[a2]"=v"(A2),[a3]"=v"(A3),
          [b0]"=v"(B0),[b1]"=v"(B1),[b2]"=v"(B2),[b3]"=v"(B3),
          [c0]"=v"(C0),[c1]"=v"(C1),[c2]"=v"(C2),[c3]"=v"(C3),
          [d0]"=v"(D0),[d1]"=v"(D1),[d2]"=v"(D2),[d3]"=v"(D3),
          [vo]"+v"(vo)
        : [xb]"s"(xb) : "memory");

    // Steady state: issue class c+4 into the just-freed set, wait vmcnt(16),
    // consume class c. Classes 4..18 issued; 0..14 consumed here.
    STEPS(E0,E1,E2,E3, A0,A1,A2,A3); CONSUME(A0,A1,A2,A3, 0);
    STEPS(A0,A1,A2,A3, B0,B1,B2,B3); CONSUME(B0,B1,B2,B3, 1);
    STEPS(B0,B1,B2,B3, C0,C1,C2,C3); CONSUME(C0,C1,C2,C3, 2);
    STEPS(C0,C1,C2,C3, D0,D1,D2,D3); CONSUME(D0,D1,D2,D3, 3);
    STEPS(D0,D1,D2,D3, E0,E1,E2,E3); CONSUME(E0,E1,E2,E3, 4);
    STEPS(E0,E1,E2,E3, A0,A1,A2,A3); CONSUME(A0,A1,A2,A3, 5);
    STEPS(A0,A1,A2,A3, B0,B1,B2,B3); CONSUME(B0,B1,B2,B3, 6);
    STEPS(B0,B1,B2,B3, C0,C1,C2,C3); CONSUME(C0,C1,C2,C3, 7);
    STEPS(C0,C1,C2,C3, D0,D1,D2,D3); CONSUME(D0,D1,D2,D3, 8);
    STEPS(D0,D1,D2,D3, E0,E1,E2,E3); CONSUME(E0,E1,E2,E3, 9);
    STEPS(E0,E1,E2,E3, A0,A1,A2,A3); CONSUME(A0,A1,A2,A3,10);
    STEPS(A0,A1,A2,A3, B0,B1,B2,B3); CONSUME(B0,B1,B2,B3,11);
    STEPS(B0,B1,B2,B3, C0,C1,C2,C3); CONSUME(C0,C1,C2,C3,12);
    STEPS(C0,C1,C2,C3, D0,D1,D2,D3); CONSUME(D0,D1,D2,D3,13);
    STEPS(D0,D1,D2,D3, E0,E1,E2,E3); CONSUME(E0,E1,E2,E3,14);
    // Tail: classes 15(A),16(B),17(C),18(D) still in flight.
    WAITP(A0,A1,A2,A3,12);           CONSUME(A0,A1,A2,A3,15);
    WAITP(B0,B1,B2,B3, 8);           CONSUME(B0,B1,B2,B3,16);
    WAITP(C0,C1,C2,C3, 4);           CONSUME(C0,C1,C2,C3,17);
    WAITP(D0,D1,D2,D3, 0);           CONSUME(D0,D1,D2,D3,18);

    // ---- per-pixel NLL ----
    float lsum = 0.0f;
    unsigned int lcnt = 0;
#pragma unroll
    for (int i = 0; i < 4; ++i)
#pragma unroll
        for (int j = 0; j < 4; ++j) {
            if (bmv[i][j] != 0u) {     // spmask already folded in
                lsum -= __logf(ts[i][j] / se[i][j] + 1e-8f);
                ++lcnt;
            }
        }

    // Wave-64 shuffle reduction -> LDS block reduction.
    for (int o = 32; o > 0; o >>= 1) {
        lsum += __shfl_down(lsum, o);
        lcnt += __shfl_down(lcnt, o);
    }
    if ((t & 63) == 0) { sL[wave] = lsum; sC[wave] = lcnt; }
    __syncthreads();

    if (t == 0) {
        float        L = sL[0] + sL[1] + sL[2] + sL[3];
        unsigned int C = sC[0] + sC[1] + sC[2] + sC[3];
        __hip_atomic_store(&pl[b], L, __ATOMIC_RELAXED,
                           __HIP_MEMORY_SCOPE_AGENT);
        __hip_atomic_store(&pc[b], C, __ATOMIC_RELAXED,
                           __HIP_MEMORY_SCOPE_AGENT);
        unsigned int g = (unsigned int)b >> 5;
        unsigned int isLast = 0u;
        unsigned int tk = __hip_atomic_fetch_add(&gt[g * 16], 1u,
                              __ATOMIC_ACQ_REL, __HIP_MEMORY_SCOPE_AGENT);
        if (tk == 31u) {
            unsigned int s = __hip_atomic_fetch_add(st, 1u,
                                 __ATOMIC_ACQ_REL, __HIP_MEMORY_SCOPE_AGENT);
            isLast = (s == NGRP - 1) ? 1u : 0u;
        }
        sC[0] = isLast;
    }
    __syncthreads();

    // Last block: reduce the 512 partials and write the scalar.
    if (sC[0]) {
        float        L = 0.0f;
        unsigned int C = 0u;
        for (int i = t; i < NBLK; i += 256) {
            L += __hip_atomic_load(&pl[i], __ATOMIC_RELAXED,
                                   __HIP_MEMORY_SCOPE_AGENT);
            C += __hip_atomic_load(&pc[i], __ATOMIC_RELAXED,
                                   __HIP_MEMORY_SCOPE_AGENT);
        }
        for (int o = 32; o > 0; o >>= 1) {
            L += __shfl_down(L, o);
            C += __shfl_down(C, o);
        }
        __syncthreads();
        if ((t & 63) == 0) { sL[wave] = L; sC[wave] = C; }
        __syncthreads();
        if (t == 0) {
            L = sL[0] + sL[1] + sL[2] + sL[3];
            C = sC[0] + sC[1] + sC[2] + sC[3];
            out[0] = L / (float)(1u + C);
        }
    }
}

extern "C" void kernel_launch(void* const* d_in, const int* in_sizes, int n_in,
                              void* d_out, int out_size, void* d_ws, size_t ws_size,
                              hipStream_t stream) {
    const float* x   = (const float*)d_in[0];   // inputs (8,19,512,512) f32
    const float* tgt = (const float*)d_in[1];   // targets (8,2048,20) f32
    const int*   sp  = (const int*)d_in[2];     // superpixels (8,512,512) i32
    const void*  spm = d_in[3];                 // spmasks (8,512,512), width detected

    unsigned int* flag = (unsigned int*)d_ws;
    unsigned int* st   = (unsigned int*)((char*)d_ws + 4);
    unsigned int* gt   = (unsigned int*)((char*)d_ws + 64);
    float*        pl   = (float*)((char*)d_ws + 1088);
    unsigned int* pc   = (unsigned int*)((char*)d_ws + 3136);
    unsigned int* bmt  = (unsigned int*)((char*)d_ws + 5184);

    prep<<<NROWS / 256, 256, 0, stream>>>(tgt, (const unsigned int*)spm,
                                          flag, st, gt, bmt);

    mcce_main<<<NBLK, 256, 0, stream>>>(x, sp, spm, bmt, flag,
                                        pl, pc, st, gt, (float*)d_out);
}

// Round 10
// 288.172 us; speedup vs baseline: 1.0091x; 1.0091x over previous
//
#include <hip/hip_runtime.h>

#define HW_   (512 * 512)   // pixels per image
#define NIMG  8
#define NC    19            // classes
#define NSP   2048          // superpixels per image
#define TC    20            // target row stride (C+1, last col sliced off)
#define NROWS (NIMG * NSP)  // 16384 target rows
#define TILE  4096          // pixels per block (16 per thread)
#define NBLK  512           // blocks (2 per CU); 512*4096 = all 2Mpx, one shot
#define NGRP  16            // completion-ticket groups (32 blocks each)

typedef float vf4 __attribute__((ext_vector_type(4)));
typedef int   vi4 __attribute__((ext_vector_type(4)));

// d_ws layout:
//   [0]    flag (uint)       spmask width: 1 -> 4-byte, 0 -> 1-byte
//   [4]    st   (uint)       super ticket
//   [64]   gt[NGRP] uints, stride 16 (64 B apart -> no same-line RMWs)
//   [1088] pl[NBLK] float    per-block loss partials (contention-free)
//   [3136] pc[NBLK] uint     per-block count partials
//   [5184] bmt[NROWS] uint   per-(image,superpixel) multi-hot bitmask

// ---------------------------------------------------------------------------
// Kernel 1: zero tickets, detect spmask width, build target bitmasks.
// (logic unchanged since round 5; see comments there)
// ---------------------------------------------------------------------------
__global__ __launch_bounds__(256) void prep(
    const float* __restrict__ tgt,
    const unsigned int* __restrict__ spm,
    unsigned int* __restrict__ flag, unsigned int* __restrict__ st,
    unsigned int* __restrict__ gt, unsigned int* __restrict__ bm) {

    int gid = blockIdx.x * 256 + threadIdx.x;
    if (gid == 0) *st = 0u;
    if (gid < NGRP) gt[gid * 16] = 0u;

    if (blockIdx.x == 1 && threadIdx.x < 64) {
        unsigned int nonlow = 0, upper = 0;
        for (int i = threadIdx.x; i < 1024; i += 64) {
            unsigned int v = spm[i];
            nonlow |= (v & 0xFEFEFEFEu);
            upper  |= (v & 0xFFFFFF00u);
        }
        unsigned long long b1 = __ballot(nonlow != 0);
        unsigned long long b2 = __ballot(upper != 0);
        if (threadIdx.x == 0)
            *flag = ((b1 == 0ull) && (b2 != 0ull)) ? 0u : 1u;
    }

    const float* row = tgt + (size_t)gid * TC;
    unsigned int m = 0;
#pragma unroll
    for (int c = 0; c < NC; ++c)
        m |= (row[c] != 0.0f ? 1u : 0u) << c;
    bm[gid] = m;
}

// ---------------------------------------------------------------------------
// Kernel 2: contiguous-run, rolling-vmcnt pipelined exp-sum + NLL.
// Round 9 proved the pipeline works (cold BW 0.6 -> 1.6 TB/s, duration
// finally sensitive to cache residency) but the 5-set window spilled
// (WRITE_SIZE 68.6 MB of scratch). This round: 3-set window (48 VGPRs);
// each step issues class c+2 (4 contiguous dwordx4 = 4 KB/wave run) and
// waits vmcnt(8) -> 2 classes (8 KB/wave) always in flight; 8 waves/CU
// -> 64 KB/CU outstanding vs ~9 KB needed for 6.3 TB/s @ 900 cyc.
// Peak live: 48 window + 32 acc + 16 bmv + ~12 addr ~= 110 < 128 (no spill).
// "+v" pass-through pins consumption after the wait; "memory" clobbers keep
// compiler vmem out of the chain (its waits would corrupt vmcnt accounting).
// ---------------------------------------------------------------------------

#define STEPS(Q0,Q1,Q2,Q3,P0,P1,P2,P3)                                     \
    asm volatile(                                                          \
        "global_load_dwordx4 %[q0], %[vo], %[xb]\n\t"                      \
        "global_load_dwordx4 %[q1], %[vo], %[xb] offset:1024\n\t"          \
        "global_load_dwordx4 %[q2], %[vo], %[xb] offset:2048\n\t"          \
        "global_load_dwordx4 %[q3], %[vo], %[xb] offset:3072\n\t"          \
        "v_add_u32 %[vo], 0x100000, %[vo]\n\t"                             \
        "s_waitcnt vmcnt(8)"                                               \
        : [q0]"=v"(Q0), [q1]"=v"(Q1), [q2]"=v"(Q2), [q3]"=v"(Q3),          \
          [p0]"+v"(P0), [p1]"+v"(P1), [p2]"+v"(P2), [p3]"+v"(P3),          \
          [vo]"+v"(vo)                                                     \
        : [xb]"s"(xb) : "memory")

#define WAITP(P0,P1,P2,P3,W)                                               \
    asm volatile("s_waitcnt vmcnt(" #W ")"                                 \
        : [p0]"+v"(P0), [p1]"+v"(P1), [p2]"+v"(P2), [p3]"+v"(P3)           \
        :: "memory")

#define ACC(Q,i,c) {                                                       \
    float e0 = __expf((Q).x), e1 = __expf((Q).y);                          \
    float e2 = __expf((Q).z), e3 = __expf((Q).w);                          \
    se[i][0] += e0; se[i][1] += e1; se[i][2] += e2; se[i][3] += e3;        \
    ts[i][0] += ((bmv[i][0] >> (c)) & 1) ? e0 : 0.0f;                      \
    ts[i][1] += ((bmv[i][1] >> (c)) & 1) ? e1 : 0.0f;                      \
    ts[i][2] += ((bmv[i][2] >> (c)) & 1) ? e2 : 0.0f;                      \
    ts[i][3] += ((bmv[i][3] >> (c)) & 1) ? e3 : 0.0f; }

#define CONSUME(S0,S1,S2,S3,c) ACC(S0,0,c) ACC(S1,1,c) ACC(S2,2,c) ACC(S3,3,c)

__global__ __launch_bounds__(256, 2) void mcce_main(
    const float* __restrict__ x,      // (N, C, H*W)
    const int*   __restrict__ sp,     // (N, H*W)
    const void*  __restrict__ spm,    // (N, H*W) mask, 1B or 4B elements
    const unsigned int* __restrict__ bmt,   // (N*NSP) bitmasks
    const unsigned int* __restrict__ flag,
    float* __restrict__ pl, unsigned int* __restrict__ pc,
    unsigned int* __restrict__ st, unsigned int* __restrict__ gt,
    float* __restrict__ out) {

    __shared__ float sL[4];
    __shared__ unsigned int sC[4];

    int b = blockIdx.x, t = threadIdx.x;
    int wave = t >> 6, lane = t & 63;
    int n   = b >> 6;                  // 64 blocks per image
    int pib = (b & 63) * TILE;         // pixel base within image
    int wp  = wave * 1024 + lane * 4;  // wave+lane pixel offset in tile

    const float* xb  = x  + (size_t)n * NC * HW_ + pib;
    const int*   spb = sp + (size_t)n * HW_ + pib;
    unsigned int flagv = *flag;

    // ---- per-pixel metadata, fully consumed BEFORE the streaming chain ----
    vi4 sq[4];
#pragma unroll
    for (int i = 0; i < 4; ++i)
        sq[i] = *(const vi4*)(spb + wp + i * 256);

    int mk[4][4];
    if (flagv) {                       // wave-uniform width branch
#pragma unroll
        for (int i = 0; i < 4; ++i) {
            vi4 m = *(const vi4*)((const int*)spm + (size_t)n * HW_ + pib + wp + i * 256);
            mk[i][0] = m.x; mk[i][1] = m.y; mk[i][2] = m.z; mk[i][3] = m.w;
        }
    } else {
#pragma unroll
        for (int i = 0; i < 4; ++i) {
            unsigned int mw = *(const unsigned int*)
                ((const unsigned char*)spm + (size_t)n * HW_ + pib + wp + i * 256);
            mk[i][0] = mw & 0xFF; mk[i][1] = (mw >> 8) & 0xFF;
            mk[i][2] = (mw >> 16) & 0xFF; mk[i][3] = (mw >> 24) & 0xFF;
        }
    }

    const unsigned int* bt = bmt + n * NSP;
    unsigned int bmv[4][4];            // bitmask, pre-ANDed with spmask
    bmv[0][0] = mk[0][0] ? bt[sq[0].x] : 0u;
    bmv[0][1] = mk[0][1] ? bt[sq[0].y] : 0u;
    bmv[0][2] = mk[0][2] ? bt[sq[0].z] : 0u;
    bmv[0][3] = mk[0][3] ? bt[sq[0].w] : 0u;
    bmv[1][0] = mk[1][0] ? bt[sq[1].x] : 0u;
    bmv[1][1] = mk[1][1] ? bt[sq[1].y] : 0u;
    bmv[1][2] = mk[1][2] ? bt[sq[1].z] : 0u;
    bmv[1][3] = mk[1][3] ? bt[sq[1].w] : 0u;
    bmv[2][0] = mk[2][0] ? bt[sq[2].x] : 0u;
    bmv[2][1] = mk[2][1] ? bt[sq[2].y] : 0u;
    bmv[2][2] = mk[2][2] ? bt[sq[2].z] : 0u;
    bmv[2][3] = mk[2][3] ? bt[sq[2].w] : 0u;
    bmv[3][0] = mk[3][0] ? bt[sq[3].x] : 0u;
    bmv[3][1] = mk[3][1] ? bt[sq[3].y] : 0u;
    bmv[3][2] = mk[3][2] ? bt[sq[3].z] : 0u;
    bmv[3][3] = mk[3][3] ? bt[sq[3].w] : 0u;

    // ---- rolling-window streaming chain (3 sets: A, B, C) ----
    float se[4][4] = {{0,0,0,0},{0,0,0,0},{0,0,0,0},{0,0,0,0}};
    float ts[4][4] = {{0,0,0,0},{0,0,0,0},{0,0,0,0},{0,0,0,0}};
    unsigned int vo = (unsigned int)(wave * 4096 + lane * 16);

    vf4 A0,A1,A2,A3, B0,B1,B2,B3, C0,C1,C2,C3;

    // Prologue: issue classes 0 (A) and 1 (B) — 8 loads, no wait.
    asm volatile(
        "global_load_dwordx4 %[a0], %[vo], %[xb]\n\t"
        "global_load_dwordx4 %[a1], %[vo], %[xb] offset:1024\n\t"
        "global_load_dwordx4 %[a2], %[vo], %[xb] offset:2048\n\t"
        "global_load_dwordx4 %[a3], %[vo], %[xb] offset:3072\n\t"
        "v_add_u32 %[vo], 0x100000, %[vo]\n\t"
        "global_load_dwordx4 %[b0], %[vo], %[xb]\n\t"
        "global_load_dwordx4 %[b1], %[vo], %[xb] offset:1024\n\t"
        "global_load_dwordx4 %[b2], %[vo], %[xb] offset:2048\n\t"
        "global_load_dwordx4 %[b3], %[vo], %[xb] offset:3072\n\t"
        "v_add_u32 %[vo], 0x100000, %[vo]"
        : [a0]"=v"(A0),[a1]"=v"(A1),[a2]"=v"(A2),[a3]"=v"(A3),
          [b0]"=v"(B0),[b1]"=v"(B1),[b2]"=v"(B2),[b3]"=v"(B3),
          [vo]"+v"(vo)
        : [xb]"s"(xb) : "memory");

    // Steady state: step k issues class k+2 into the just-freed set, waits
    // vmcnt(8) (2 classes in flight), consumes class k. k = 0..16.
    STEPS(C0,C1,C2,C3, A0,A1,A2,A3); CONSUME(A0,A1,A2,A3, 0);
    STEPS(A0,A1,A2,A3, B0,B1,B2,B3); CONSUME(B0,B1,B2,B3, 1);
    STEPS(B0,B1,B2,B3, C0,C1,C2,C3); CONSUME(C0,C1,C2,C3, 2);
    STEPS(C0,C1,C2,C3, A0,A1,A2,A3); CONSUME(A0,A1,A2,A3, 3);
    STEPS(A0,A1,A2,A3, B0,B1,B2,B3); CONSUME(B0,B1,B2,B3, 4);
    STEPS(B0,B1,B2,B3, C0,C1,C2,C3); CONSUME(C0,C1,C2,C3, 5);
    STEPS(C0,C1,C2,C3, A0,A1,A2,A3); CONSUME(A0,A1,A2,A3, 6);
    STEPS(A0,A1,A2,A3, B0,B1,B2,B3); CONSUME(B0,B1,B2,B3, 7);
    STEPS(B0,B1,B2,B3, C0,C1,C2,C3); CONSUME(C0,C1,C2,C3, 8);
    STEPS(C0,C1,C2,C3, A0,A1,A2,A3); CONSUME(A0,A1,A2,A3, 9);
    STEPS(A0,A1,A2,A3, B0,B1,B2,B3); CONSUME(B0,B1,B2,B3,10);
    STEPS(B0,B1,B2,B3, C0,C1,C2,C3); CONSUME(C0,C1,C2,C3,11);
    STEPS(C0,C1,C2,C3, A0,A1,A2,A3); CONSUME(A0,A1,A2,A3,12);
    STEPS(A0,A1,A2,A3, B0,B1,B2,B3); CONSUME(B0,B1,B2,B3,13);
    STEPS(B0,B1,B2,B3, C0,C1,C2,C3); CONSUME(C0,C1,C2,C3,14);
    STEPS(C0,C1,C2,C3, A0,A1,A2,A3); CONSUME(A0,A1,A2,A3,15);
    STEPS(A0,A1,A2,A3, B0,B1,B2,B3); CONSUME(B0,B1,B2,B3,16);
    // Tail: class 17 (C) and 18 (A) still in flight.
    WAITP(C0,C1,C2,C3,4);            CONSUME(C0,C1,C2,C3,17);
    WAITP(A0,A1,A2,A3,0);            CONSUME(A0,A1,A2,A3,18);

    // ---- per-pixel NLL ----
    float lsum = 0.0f;
    unsigned int lcnt = 0;
#pragma unroll
    for (int i = 0; i < 4; ++i)
#pragma unroll
        for (int j = 0; j < 4; ++j) {
            if (bmv[i][j] != 0u) {     // spmask already folded in
                lsum -= __logf(ts[i][j] / se[i][j] + 1e-8f);
                ++lcnt;
            }
        }

    // Wave-64 shuffle reduction -> LDS block reduction.
    for (int o = 32; o > 0; o >>= 1) {
        lsum += __shfl_down(lsum, o);
        lcnt += __shfl_down(lcnt, o);
    }
    if ((t & 63) == 0) { sL[wave] = lsum; sC[wave] = lcnt; }
    __syncthreads();

    if (t == 0) {
        float        L = sL[0] + sL[1] + sL[2] + sL[3];
        unsigned int C = sC[0] + sC[1] + sC[2] + sC[3];
        __hip_atomic_store(&pl[b], L, __ATOMIC_RELAXED,
                           __HIP_MEMORY_SCOPE_AGENT);
        __hip_atomic_store(&pc[b], C, __ATOMIC_RELAXED,
                           __HIP_MEMORY_SCOPE_AGENT);
        unsigned int g = (unsigned int)b >> 5;
        unsigned int isLast = 0u;
        unsigned int tk = __hip_atomic_fetch_add(&gt[g * 16], 1u,
                              __ATOMIC_ACQ_REL, __HIP_MEMORY_SCOPE_AGENT);
        if (tk == 31u) {
            unsigned int s = __hip_atomic_fetch_add(st, 1u,
                                 __ATOMIC_ACQ_REL, __HIP_MEMORY_SCOPE_AGENT);
            isLast = (s == NGRP - 1) ? 1u : 0u;
        }
        sC[0] = isLast;
    }
    __syncthreads();

    // Last block: reduce the 512 partials and write the scalar.
    if (sC[0]) {
        float        L = 0.0f;
        unsigned int C = 0u;
        for (int i = t; i < NBLK; i += 256) {
            L += __hip_atomic_load(&pl[i], __ATOMIC_RELAXED,
                                   __HIP_MEMORY_SCOPE_AGENT);
            C += __hip_atomic_load(&pc[i], __ATOMIC_RELAXED,
                                   __HIP_MEMORY_SCOPE_AGENT);
        }
        for (int o = 32; o > 0; o >>= 1) {
            L += __shfl_down(L, o);
            C += __shfl_down(C, o);
        }
        __syncthreads();
        if ((t & 63) == 0) { sL[wave] = L; sC[wave] = C; }
        __syncthreads();
        if (t == 0) {
            L = sL[0] + sL[1] + sL[2] + sL[3];
            C = sC[0] + sC[1] + sC[2] + sC[3];
            out[0] = L / (float)(1u + C);
        }
    }
}

extern "C" void kernel_launch(void* const* d_in, const int* in_sizes, int n_in,
                              void* d_out, int out_size, void* d_ws, size_t ws_size,
                              hipStream_t stream) {
    const float* x   = (const float*)d_in[0];   // inputs (8,19,512,512) f32
    const float* tgt = (const float*)d_in[1];   // targets (8,2048,20) f32
    const int*   sp  = (const int*)d_in[2];     // superpixels (8,512,512) i32
    const void*  spm = d_in[3];                 // spmasks (8,512,512), width detected

    unsigned int* flag = (unsigned int*)d_ws;
    unsigned int* st   = (unsigned int*)((char*)d_ws + 4);
    unsigned int* gt   = (unsigned int*)((char*)d_ws + 64);
    float*        pl   = (float*)((char*)d_ws + 1088);
    unsigned int* pc   = (unsigned int*)((char*)d_ws + 3136);
    unsigned int* bmt  = (unsigned int*)((char*)d_ws + 5184);

    prep<<<NROWS / 256, 256, 0, stream>>>(tgt, (const unsigned int*)spm,
                                          flag, st, gt, bmt);

    mcce_main<<<NBLK, 256, 0, stream>>>(x, sp, spm, bmt, flag,
                                        pl, pc, st, gt, (float*)d_out);
}